// Round 7
// baseline (195.231 us; speedup 1.0000x reference)
//
#include <hip/hip_runtime.h>
#include <math.h>

// Problem constants (fixed shapes)
#define DIM    4096
#define NH     32
#define NKV    8
#define HD     128
#define BS     16
#define KVLEN  4096
#define LASTPOS 4095
#define QKV_COLS 6144   // 4096 q + 1024 k + 1024 v
#define NKC    64       // k-chunks for split-K projections

typedef float f32x4 __attribute__((ext_vector_type(4)));

// ws layout (floats):
//   qkv   : [16][6144]             @ 0          (98304)
//   attn  : [16][4096]             @ 98304      (65536)
//   part  : [4096 blocks][4][132]  @ 163840     (2162688)
//   pq    : [64][16][6144]         @ 2326528    (6291456)
//   pw    : [64][16][4096]         @ 8617984    (4194304)   end 12812288 (~51MB)
#define WS_QKV   0
#define WS_ATTN  98304
#define WS_PART  163840
#define WS_PQ    2326528
#define WS_PW    8617984

// ---------------------------------------------------------------------------
// K1a: qkv partials. block: 256 thr, 2 cols/thread (512 cols); grid (12, 64).
// ---------------------------------------------------------------------------
__global__ __launch_bounds__(256) void qkv_projA(
    const float* __restrict__ x, const float* __restrict__ wq,
    const float* __restrict__ wk, const float* __restrict__ wv,
    float* __restrict__ pq) {
  __shared__ float xs[16 * 64];
  const int tid = threadIdx.x;
  const int col = (blockIdx.x * 256 + tid) * 2;   // block-uniform matrix select
  const int kc = blockIdx.y;
  const int k0 = kc * 64;

  for (int i = tid; i < 1024; i += 256) {
    int b = i >> 6, k = i & 63;
    xs[i] = x[b * DIM + k0 + k];
  }
  __syncthreads();

  const float* w;
  int wstride, wcol;
  if (col < 4096)      { w = wq; wstride = 4096; wcol = col; }
  else if (col < 5120) { w = wk; wstride = 1024; wcol = col - 4096; }
  else                 { w = wv; wstride = 1024; wcol = col - 5120; }
  const float* wp = w + (size_t)k0 * wstride + wcol;

  float acc0[16], acc1[16];
#pragma unroll
  for (int b = 0; b < 16; ++b) { acc0[b] = 0.f; acc1[b] = 0.f; }

#pragma unroll 2
  for (int k = 0; k < 64; k += 4) {
    float2 w0 = *(const float2*)(wp + (size_t)(k + 0) * wstride);
    float2 w1 = *(const float2*)(wp + (size_t)(k + 1) * wstride);
    float2 w2 = *(const float2*)(wp + (size_t)(k + 2) * wstride);
    float2 w3 = *(const float2*)(wp + (size_t)(k + 3) * wstride);
#pragma unroll
    for (int b = 0; b < 16; ++b) {
      float4 xb = *(const float4*)(&xs[b * 64 + k]);
      acc0[b] += xb.x * w0.x + xb.y * w1.x + xb.z * w2.x + xb.w * w3.x;
      acc1[b] += xb.x * w0.y + xb.y * w1.y + xb.z * w2.y + xb.w * w3.y;
    }
  }
#pragma unroll
  for (int b = 0; b < 16; ++b) {
    *(float2*)(&pq[((size_t)kc * 16 + b) * QKV_COLS + col]) = make_float2(acc0[b], acc1[b]);
  }
}

// ---------------------------------------------------------------------------
// K1b: reduce 64 qkv partials + fused RoPE (+ q scale).
// ---------------------------------------------------------------------------
__global__ __launch_bounds__(256) void qkv_projB(
    const float* __restrict__ pq, float* __restrict__ qkv,
    const float* __restrict__ fc, const float* __restrict__ fs) {
  int t = blockIdx.x * 256 + threadIdx.x;       // 0..49151
  int b = t / 3072, pr = t % 3072;
  int col = 2 * pr;
  float e = 0.f, o = 0.f;
#pragma unroll 8
  for (int kc = 0; kc < NKC; ++kc) {
    float2 v = *(const float2*)(&pq[((size_t)kc * 16 + b) * QKV_COLS + col]);
    e += v.x; o += v.y;
  }
  float re = e, im = o;
  if (col < 5120) {  // q or k: rope
    int i = (col & 127) >> 1;
    float c = fc[i], s = fs[i];
    float scale = (col < 4096) ? 0.08838834764831845f : 1.0f;
    re = (e * c - o * s) * scale;
    im = (e * s + o * c) * scale;
  }
  *(float2*)(&qkv[b * QKV_COLS + col]) = make_float2(re, im);
}

// ---------------------------------------------------------------------------
// K3: attention partials. 256 thr = 4 waves, each wave independently owns
// 32 kv rows; ONE final __syncthreads + LDS combine per block (128 rows).
// Scores: 16-lane group per K row (4 rows in parallel), DENSE loads:
//   lane ql covers d=[ql*4,ql*4+4) and [64+ql*4, 64+ql*4+4).
//   shfl_xor(1,2,4,8) reduce; lane keeps sv8[it] = score(row 4it+p, head ql&3).
// Softmax: per-wave via regs + shfl_xor(16,32).
// PV: half-wave owns a row, lane covers d=dq*4..+4 (dense), P pulled via shfl.
// ---------------------------------------------------------------------------
__global__ __launch_bounds__(256, 4) void attn_partial(
    const float* __restrict__ cache_k, const float* __restrict__ cache_v,
    const float* __restrict__ qkv, float* __restrict__ part) {
  __shared__ float red[4][4][130];              // [wave][head][128 o | m | l]
  const int tid = threadIdx.x;
  const int w = tid >> 6, lane = tid & 63;
  const int p = lane >> 4, ql = lane & 15;
  const int chunk = blockIdx.x & 31;            // 128-row chunk
  const int bg = blockIdx.x >> 5;
  const int b = bg >> 3, g = bg & 7;
  const int t0w = chunk * 128 + w * 32;         // first kv row of this wave

  // Q fragments (dense): head h, d = [ql*4,+4) and [64+ql*4,+4)
  const float* qbase = qkv + b * QKV_COLS + g * 512;
  f32x4 qA[4], qB[4];
#pragma unroll
  for (int h = 0; h < 4; ++h) {
    qA[h] = *(const f32x4*)(qbase + h * 128 + ql * 4);
    qB[h] = *(const f32x4*)(qbase + h * 128 + 64 + ql * 4);
  }

  const float* kbase = cache_k + ((size_t)b * 4096 * 8 + g) * 128;
  const float* xk    = qkv + b * QKV_COLS + 4096 + g * 128;

  // ---- scores: sv8[it] = S[row 4it+p][head ql&3] ----
  float sv8[8];
#pragma unroll
  for (int it = 0; it < 8; ++it) {
    int t = t0w + it * 4 + p;
    const float* krow = (t == LASTPOS) ? xk : (kbase + (size_t)t * 1024);
    f32x4 k0 = *(const f32x4*)(krow + ql * 4);
    f32x4 k1 = *(const f32x4*)(krow + 64 + ql * 4);
    float s[4];
#pragma unroll
    for (int h = 0; h < 4; ++h) {
      s[h] = k0[0]*qA[h][0] + k0[1]*qA[h][1] + k0[2]*qA[h][2] + k0[3]*qA[h][3]
           + k1[0]*qB[h][0] + k1[1]*qB[h][1] + k1[2]*qB[h][2] + k1[3]*qB[h][3];
    }
#pragma unroll
    for (int off = 1; off < 16; off <<= 1) {
#pragma unroll
      for (int h = 0; h < 4; ++h) s[h] += __shfl_xor(s[h], off);
    }
    int hsel = ql & 3;
    float v = s[0];
    if (hsel == 1) v = s[1];
    if (hsel == 2) v = s[2];
    if (hsel == 3) v = s[3];
    sv8[it] = v;
  }

  // ---- per-wave softmax for head (ql&3) over this wave's 32 rows ----
  float m = -1e30f;
#pragma unroll
  for (int it = 0; it < 8; ++it) m = fmaxf(m, sv8[it]);
  m = fmaxf(m, __shfl_xor(m, 16));
  m = fmaxf(m, __shfl_xor(m, 32));
  float l = 0.f;
#pragma unroll
  for (int it = 0; it < 8; ++it) { sv8[it] = __expf(sv8[it] - m); l += sv8[it]; }
  l += __shfl_xor(l, 16);
  l += __shfl_xor(l, 32);

  // ---- PV: half-wave owns a row; lane covers d = dq*4..dq*4+3 ----
  const float* vbase = cache_v + ((size_t)b * 4096 * 8 + g) * 128;
  const float* xv    = qkv + b * QKV_COLS + 5120 + g * 128;
  const int h2 = lane >> 5;
  const int dq = lane & 31;
  f32x4 acc[4];
#pragma unroll
  for (int h = 0; h < 4; ++h) acc[h] = (f32x4)(0.f);

#pragma unroll
  for (int jj = 0; jj < 16; ++jj) {
    int lr = 2 * jj + h2;                     // local row 0..31
    int t = t0w + lr;
    const float* vrow = (t == LASTPOS) ? xv : (vbase + (size_t)t * 1024);
    f32x4 vv = *(const f32x4*)(vrow + dq * 4);
    float sreg = sv8[jj >> 1];                // compile-time index
    int srcb = (lr & 3) << 4;
    float p0 = __shfl(sreg, srcb + 0);
    float p1 = __shfl(sreg, srcb + 1);
    float p2 = __shfl(sreg, srcb + 2);
    float p3 = __shfl(sreg, srcb + 3);
    acc[0] += p0 * vv;
    acc[1] += p1 * vv;
    acc[2] += p2 * vv;
    acc[3] += p3 * vv;
  }
#pragma unroll
  for (int h = 0; h < 4; ++h) {
    acc[h][0] += __shfl_xor(acc[h][0], 32);
    acc[h][1] += __shfl_xor(acc[h][1], 32);
    acc[h][2] += __shfl_xor(acc[h][2], 32);
    acc[h][3] += __shfl_xor(acc[h][3], 32);
  }
  if (lane < 32) {
#pragma unroll
    for (int h = 0; h < 4; ++h)
      *(f32x4*)(&red[w][h][dq * 4]) = acc[h];
  }
  if (lane < 4) { red[w][lane][128] = m; red[w][lane][129] = l; }
  __syncthreads();

  // ---- block combine: 4 waves' partials -> one (m,l,o) per head ----
  for (int item = tid; item < 512; item += 256) {
    int h = item >> 7, d = item & 127;
    float M = -1e30f;
#pragma unroll
    for (int w2 = 0; w2 < 4; ++w2) M = fmaxf(M, red[w2][h][128]);
    float num = 0.f, den = 0.f;
#pragma unroll
    for (int w2 = 0; w2 < 4; ++w2) {
      float wgt = __expf(red[w2][h][128] - M);
      num += wgt * red[w2][h][d];
      den += wgt * red[w2][h][129];
    }
    size_t pi = ((size_t)blockIdx.x * 4 + h) * 132;
    part[pi + d] = num;
    if (d == 0) { part[pi + 128] = M; part[pi + 129] = den; }
  }
}

// ---------------------------------------------------------------------------
// K4: merge 32 chunk-partials per (bg,h,d) -> attn_out. 65536 threads.
// ---------------------------------------------------------------------------
__global__ __launch_bounds__(256) void attn_combine(
    const float* __restrict__ part, float* __restrict__ attn_out) {
  int t = blockIdx.x * 256 + threadIdx.x;   // 0..65535
  int d = t & 127, h = (t >> 7) & 3, bg = t >> 9;
  int b = bg >> 3, g = bg & 7;
  float M = -1e30f;
  float ms[32];
#pragma unroll
  for (int c = 0; c < 32; ++c) {
    ms[c] = part[((size_t)(bg * 32 + c) * 4 + h) * 132 + 128];
    M = fmaxf(M, ms[c]);
  }
  float num = 0.f, den = 0.f;
#pragma unroll 4
  for (int c = 0; c < 32; ++c) {
    const float* pr = part + ((size_t)(bg * 32 + c) * 4 + h) * 132;
    float wgt = __expf(ms[c] - M);
    num += wgt * pr[d];
    den += wgt * pr[129];
  }
  attn_out[b * DIM + (g * 4 + h) * 128 + d] = num / den;
}

// ---------------------------------------------------------------------------
// K5a: wo partials. block: 256 thr, 2 cols/thread (512 cols); grid (8, 64).
// ---------------------------------------------------------------------------
__global__ __launch_bounds__(256) void out_projA(
    const float* __restrict__ attn, const float* __restrict__ wo,
    float* __restrict__ pw) {
  __shared__ float xs[16 * 64];
  const int tid = threadIdx.x;
  const int col = (blockIdx.x * 256 + tid) * 2;  // 0..4094
  const int kc = blockIdx.y;
  const int k0 = kc * 64;

  for (int i = tid; i < 1024; i += 256) {
    int b = i >> 6, k = i & 63;
    xs[i] = attn[b * DIM + k0 + k];
  }
  __syncthreads();

  const float* wp = wo + (size_t)k0 * 4096 + col;
  float acc0[16], acc1[16];
#pragma unroll
  for (int b = 0; b < 16; ++b) { acc0[b] = 0.f; acc1[b] = 0.f; }

#pragma unroll 2
  for (int k = 0; k < 64; k += 4) {
    float2 w0 = *(const float2*)(wp + (size_t)(k + 0) * 4096);
    float2 w1 = *(const float2*)(wp + (size_t)(k + 1) * 4096);
    float2 w2 = *(const float2*)(wp + (size_t)(k + 2) * 4096);
    float2 w3 = *(const float2*)(wp + (size_t)(k + 3) * 4096);
#pragma unroll
    for (int b = 0; b < 16; ++b) {
      float4 xb = *(const float4*)(&xs[b * 64 + k]);
      acc0[b] += xb.x * w0.x + xb.y * w1.x + xb.z * w2.x + xb.w * w3.x;
      acc1[b] += xb.x * w0.y + xb.y * w1.y + xb.z * w2.y + xb.w * w3.y;
    }
  }
#pragma unroll
  for (int b = 0; b < 16; ++b) {
    *(float2*)(&pw[((size_t)kc * 16 + b) * DIM + col]) = make_float2(acc0[b], acc1[b]);
  }
}

// ---------------------------------------------------------------------------
// K5b: reduce 64 wo partials -> d_out.
// ---------------------------------------------------------------------------
__global__ __launch_bounds__(256) void out_projB(
    const float* __restrict__ pw, float* __restrict__ out) {
  int t = blockIdx.x * 256 + threadIdx.x;  // 65536
  int b = t >> 12, col = t & 4095;
  float sum = 0.f;
#pragma unroll 8
  for (int kc = 0; kc < NKC; ++kc)
    sum += pw[((size_t)kc * 16 + b) * DIM + col];
  out[b * DIM + col] = sum;
}

// ---------------------------------------------------------------------------
extern "C" void kernel_launch(void* const* d_in, const int* in_sizes, int n_in,
                              void* d_out, int out_size, void* d_ws, size_t ws_size,
                              hipStream_t stream) {
  const float* x  = (const float*)d_in[0];
  const float* wq = (const float*)d_in[1];
  const float* wk = (const float*)d_in[2];
  const float* wv = (const float*)d_in[3];
  const float* wo = (const float*)d_in[4];
  const float* ck = (const float*)d_in[5];
  const float* cv = (const float*)d_in[6];
  const float* fc = (const float*)d_in[7];
  const float* fs = (const float*)d_in[8];

  float* ws_f  = (float*)d_ws;
  float* qkv   = ws_f + WS_QKV;
  float* attn  = ws_f + WS_ATTN;
  float* part  = ws_f + WS_PART;
  float* pq    = ws_f + WS_PQ;
  float* pw    = ws_f + WS_PW;
  float* out   = (float*)d_out;

  qkv_projA<<<dim3(12, NKC), 256, 0, stream>>>(x, wq, wk, wv, pq);
  qkv_projB<<<192, 256, 0, stream>>>(pq, qkv, fc, fs);
  attn_partial<<<4096, 256, 0, stream>>>(ck, cv, qkv, part);
  attn_combine<<<256, 256, 0, stream>>>(part, attn);
  out_projA<<<dim3(8, NKC), 256, 0, stream>>>(attn, wo, pw);
  out_projB<<<256, 256, 0, stream>>>(pw, out);
}